// Round 2
// baseline (210.291 us; speedup 1.0000x reference)
//
#include <hip/hip_runtime.h>
#include <hip/hip_bf16.h>

#define N_NODES 50000
#define N_EDGES 800000
#define DIM 64
#define NHEAD 2
#define HD 128     // NHEAD * DIM
#define NCOL 448   // 128 q + 128 k + 128 vc + 64 skipc
#define MAXDEG 64  // ELL row stride; max Poisson(16) deg over 50k nodes ~ 45

#define ACH 2048     // edges per edge-block
#define EDGE_BLKS 391 // ceil(800000/2048)

#define PREP_B 112  // 448*64/256
#define PROJ_B 782  // ceil(50000/64)

// q pre-scale: 1/sqrt(64) * 1/ln(2)  -> logits are in exp2 domain
#define QSCALE 0.18033688011112042f

typedef short bf16x8 __attribute__((ext_vector_type(8)));
typedef float f32x16 __attribute__((ext_vector_type(16)));
typedef float f32x2 __attribute__((ext_vector_type(2)));

__device__ __forceinline__ unsigned short f2bf(float f) {
    unsigned u = __float_as_uint(f);
    unsigned r = (u + 0x7fffu + ((u >> 16) & 1u)) >> 16;   // RNE
    return (unsigned short)r;
}
// fp8 e4m3 HW converts (gfx950 OCP): encode f32 -> 1 byte
__device__ __forceinline__ unsigned char f2fp8(float f) {
    int r = __builtin_amdgcn_cvt_pk_fp8_f32(f, f, 0, false);
    return (unsigned char)(r & 0xff);
}

// ------- merged: folded-weight prep ∥ direct ELL build (deg pre-zeroed by memset) ----
// blocks [0,PREP_B): WallT[448][64] bf16 + ball[448] (+ zero stats)
// blocks [PREP_B, PREP_B+EDGE_BLKS): 2048 edges each; one global atomicAdd per edge
//   into deg[dst], scatter u16 src into elist[dst*64+slot]. No LDS, no barriers.
__global__ __launch_bounds__(256) void k_pb(
    const int* __restrict__ ei,
    const float* __restrict__ Wq, const float* __restrict__ bq,
    const float* __restrict__ Wk, const float* __restrict__ bk,
    const float* __restrict__ Wv, const float* __restrict__ bv,
    const float* __restrict__ Wskip, const float* __restrict__ bskip,
    const float* __restrict__ Wc, const float* __restrict__ bc,
    unsigned short* __restrict__ WallT, float* __restrict__ ball,
    int* __restrict__ deg, unsigned short* __restrict__ elist,
    double* __restrict__ stats)
{
    const int t = threadIdx.x;
    if (blockIdx.x < PREP_B) {
        int gid = blockIdx.x * 256 + t;   // 0..28671
        if (gid == 0) { stats[0] = 0.0; stats[1] = 0.0; }
        const int j = gid >> 6;   // output column 0..447
        const int d = gid & 63;   // k index
        float w, bb;
        if (j < 128) {
            w = Wq[d * HD + j] * QSCALE;
            bb = bq[j] * QSCALE;
        } else if (j < 256) {
            int jj = j - 128;
            w = Wk[d * HD + jj];
            bb = bk[jj];
        } else if (j < 384) {
            int jj = j - 256;
            int h = jj >> 6, jc = jj & 63;
            float s = 0.f, sb = 0.f;
            for (int c = 0; c < 64; c++) {
                float wc = Wc[(h * 64 + c) * DIM + jc];
                s  += Wv[d * HD + h * 64 + c] * wc;
                sb += bv[h * 64 + c] * wc;
            }
            w = s; bb = sb;
        } else {
            int jj = j - 384;
            float s = 0.f, sb = bc[jj];
            for (int c = 0; c < HD; c++) {
                float wc = Wc[c * DIM + jj];
                s  += Wskip[d * HD + c] * wc;
                sb += bskip[c] * wc;
            }
            w = s; bb = sb;
        }
        WallT[gid] = f2bf(w);
        if (d == 0) ball[j] = bb;
        return;
    }
    // ---- direct ELL build: stream edges, one atomic per edge ----
    const int e0 = (blockIdx.x - PREP_B) * ACH;
#pragma unroll 2
    for (int i = t; i < ACH; i += 256) {
        int e = e0 + i;
        if (e < N_EDGES) {
            int src = ei[e];
            int d = ei[N_EDGES + e];
            int sl = atomicAdd(&deg[d], 1);
            if (sl < MAXDEG)
                elist[(size_t)d * MAXDEG + sl] = (unsigned short)src;
        }
    }
}

// ------- MFMA projection GEMM (pure; ELL build moved into k_pb) -------
// one 64-node tile of [N x 64] @ [64 x 448] (x read directly)
//   C/D mapping: col=lane&31, row=(reg&3)+8*(reg>>2)+4*(lane>>5)
//   outputs: q f32 [N,128] | kv fp8 [N,256] interleaved | skipc f32 [N,64]
//   kv byte layout per 16B group i: [h0 ch 8i..8i+7 | h1 ch 8i..8i+7], K then V.
__global__ __launch_bounds__(256) void k_ep(
    const float* __restrict__ x,
    const unsigned short* __restrict__ WallT, const float* __restrict__ ball,
    float* __restrict__ q, unsigned char* __restrict__ kv, float* __restrict__ skipc)
{
    const int blk = blockIdx.x;
    const int t = threadIdx.x;
    const int w = t >> 6;
    const int lane = t & 63;
    const int col = lane & 31;
    const int khalf = lane >> 5;
    const int n0 = blk * 64 + (w >> 1) * 32;
    const int ct0 = (w & 1) * 7;
    const int rowbase = 4 * khalf;

    int nread = n0 + col; if (nread >= N_NODES) nread = N_NODES - 1;
    const float* ap = x + (size_t)nread * 64 + khalf * 8;
    bf16x8 afrag[4];
#pragma unroll
    for (int kk = 0; kk < 4; kk++) {
        float4 xa = *((const float4*)(ap + kk * 16));
        float4 xb4 = *((const float4*)(ap + kk * 16 + 4));
        bf16x8 f;
        f[0] = (short)f2bf(xa.x); f[1] = (short)f2bf(xa.y);
        f[2] = (short)f2bf(xa.z); f[3] = (short)f2bf(xa.w);
        f[4] = (short)f2bf(xb4.x); f[5] = (short)f2bf(xb4.y);
        f[6] = (short)f2bf(xb4.z); f[7] = (short)f2bf(xb4.w);
        afrag[kk] = f;
    }

    for (int tt = 0; tt < 7; tt++) {
        const int gc = (ct0 + tt) * 32 + col;
        const float b = ball[gc];
        f32x16 acc;
#pragma unroll
        for (int r = 0; r < 16; r++) acc[r] = b;
        const unsigned short* bp = WallT + (size_t)gc * 64 + khalf * 8;
#pragma unroll
        for (int kk = 0; kk < 4; kk++) {
            bf16x8 bfrag = *((const bf16x8*)(bp + kk * 16));
            acc = __builtin_amdgcn_mfma_f32_32x32x16_bf16(afrag[kk], bfrag, acc, 0, 0, 0);
        }
        if (gc < 128) {
#pragma unroll
            for (int r = 0; r < 16; r++) {
                int node = n0 + (r & 3) + 8 * (r >> 2) + rowbase;
                if (node < N_NODES) q[(size_t)node * HD + gc] = acc[r];
            }
        } else if (gc < 384) {
            int ch = gc - 128;           // 0..255 (K: 0..127, V: 128..255)
            int half = ch >> 7;          // 0=K, 1=V
            int cc = ch & 127;
            int h = cc >> 6, c = cc & 63;
            int pos = half * 128 + ((c >> 3) << 4) + (h << 3) + (c & 7);
#pragma unroll
            for (int r = 0; r < 16; r++) {
                int node = n0 + (r & 3) + 8 * (r >> 2) + rowbase;
                if (node < N_NODES) kv[(size_t)node * 256 + pos] = f2fp8(acc[r]);
            }
        } else {
#pragma unroll
            for (int r = 0; r < 16; r++) {
                int node = n0 + (r & 3) + 8 * (r >> 2) + rowbase;
                if (node < N_NODES) skipc[(size_t)node * DIM + (gc - 384)] = acc[r];
            }
        }
    }
}

// -------- fused attention: fp8 kv gather, 8-edge-parallel softmax + skipc + stats ----
// 4 waves/block, one wave per dst node; 8 groups x 8 lanes, one edge per group/iter.
// kv row (256B fp8): 16B groups [h0 8ch | h1 8ch], K region then V region.
// One uint4 load each for K and V per lane. q pre-scaled -> exp2 direct.
__global__ __launch_bounds__(256) void k_attn(
    const float* __restrict__ q, const unsigned char* __restrict__ kv,
    const float* __restrict__ skipc,
    const int* __restrict__ deg, const unsigned short* __restrict__ elist,
    float* __restrict__ out, float* __restrict__ parts)
{
    const int w = threadIdx.x >> 6;
    const int lane = threadIdx.x & 63;
    const int g = lane >> 3;   // edge group 0..7
    const int j = lane & 7;    // channels 8j..8j+7 of each head
    const int n = blockIdx.x * 4 + w;
    const f32x2* qp = (const f32x2*)(q + (size_t)n * HD);
    f32x2 q0[4], q1[4];
#pragma unroll
    for (int i = 0; i < 4; i++) { q0[i] = qp[4 * j + i]; q1[i] = qp[32 + 4 * j + i]; }
    const int myE = elist[(size_t)n * MAXDEG + lane];   // full ELL row, coalesced u16
    f32x2 acc0[4], acc1[4];
#pragma unroll
    for (int i = 0; i < 4; i++) {
        acc0[i] = (f32x2){0.f, 0.f};
        acc1[i] = (f32x2){0.f, 0.f};
    }
    float l0 = 0.f, l1 = 0.f;
    int dg = deg[n]; if (dg > MAXDEG) dg = MAXDEG;
    for (int b0 = 0; b0 < dg; b0 += 8) {
        int idx = b0 + g;
        bool valid = idx < dg;
        int s = __shfl(myE, valid ? idx : 0, 64);
        const uint4* kp = (const uint4*)(kv + (size_t)s * 256);
        uint4 K = kp[j];       // h0 c8j..8j+7 (x,y) | h1 c8j..8j+7 (z,w)
        uint4 V = kp[8 + j];
        f32x2 p0v = q0[0] * __builtin_amdgcn_cvt_pk_f32_fp8(K.x, false);
        p0v += q0[1] * __builtin_amdgcn_cvt_pk_f32_fp8(K.x, true);
        p0v += q0[2] * __builtin_amdgcn_cvt_pk_f32_fp8(K.y, false);
        p0v += q0[3] * __builtin_amdgcn_cvt_pk_f32_fp8(K.y, true);
        f32x2 p1v = q1[0] * __builtin_amdgcn_cvt_pk_f32_fp8(K.z, false);
        p1v += q1[1] * __builtin_amdgcn_cvt_pk_f32_fp8(K.z, true);
        p1v += q1[2] * __builtin_amdgcn_cvt_pk_f32_fp8(K.w, false);
        p1v += q1[3] * __builtin_amdgcn_cvt_pk_f32_fp8(K.w, true);
        float p0 = p0v[0] + p0v[1];
        float p1 = p1v[0] + p1v[1];
#pragma unroll
        for (int off = 1; off < 8; off <<= 1) {
            p0 += __shfl_xor(p0, off, 64);
            p1 += __shfl_xor(p1, off, 64);
        }
        float w0 = valid ? __builtin_amdgcn_exp2f(p0) : 0.f;
        float w1 = valid ? __builtin_amdgcn_exp2f(p1) : 0.f;
        l0 += w0; l1 += w1;
        f32x2 w0v = {w0, w0}, w1v = {w1, w1};
        acc0[0] += w0v * __builtin_amdgcn_cvt_pk_f32_fp8(V.x, false);
        acc0[1] += w0v * __builtin_amdgcn_cvt_pk_f32_fp8(V.x, true);
        acc0[2] += w0v * __builtin_amdgcn_cvt_pk_f32_fp8(V.y, false);
        acc0[3] += w0v * __builtin_amdgcn_cvt_pk_f32_fp8(V.y, true);
        acc1[0] += w1v * __builtin_amdgcn_cvt_pk_f32_fp8(V.z, false);
        acc1[1] += w1v * __builtin_amdgcn_cvt_pk_f32_fp8(V.z, true);
        acc1[2] += w1v * __builtin_amdgcn_cvt_pk_f32_fp8(V.w, false);
        acc1[3] += w1v * __builtin_amdgcn_cvt_pk_f32_fp8(V.w, true);
    }
    // ---- cross-group reduction (once per node) ----
    float* a0 = (float*)acc0;
    float* a1 = (float*)acc1;
#pragma unroll
    for (int off = 8; off < 64; off <<= 1) {
        l0 += __shfl_xor(l0, off, 64);
        l1 += __shfl_xor(l1, off, 64);
#pragma unroll
        for (int i = 0; i < 8; i++) {
            a0[i] += __shfl_xor(a0[i], off, 64);
            a1[i] += __shfl_xor(a1[i], off, 64);
        }
    }
    if (g == 0) {
        float inv0 = 1.f / (l0 + 1e-16f), inv1 = 1.f / (l1 + 1e-16f);
        const float4* sk = (const float4*)(skipc + (size_t)n * DIM);
        float4 sa = sk[2 * j], sb = sk[2 * j + 1];
        float o[8];
        o[0] = a0[0] * inv0 + a1[0] * inv1 + sa.x;
        o[1] = a0[1] * inv0 + a1[1] * inv1 + sa.y;
        o[2] = a0[2] * inv0 + a1[2] * inv1 + sa.z;
        o[3] = a0[3] * inv0 + a1[3] * inv1 + sa.w;
        o[4] = a0[4] * inv0 + a1[4] * inv1 + sb.x;
        o[5] = a0[5] * inv0 + a1[5] * inv1 + sb.y;
        o[6] = a0[6] * inv0 + a1[6] * inv1 + sb.z;
        o[7] = a0[7] * inv0 + a1[7] * inv1 + sb.w;
        float4 r0 = {o[0], o[1], o[2], o[3]}, r1 = {o[4], o[5], o[6], o[7]};
        float4* op = (float4*)(out + (size_t)n * DIM);
        op[2 * j] = r0; op[2 * j + 1] = r1;
        float s_ = 0.f, ss = 0.f;
#pragma unroll
        for (int i = 0; i < 8; i++) { s_ += o[i]; ss += o[i] * o[i]; }
#pragma unroll
        for (int off = 1; off < 8; off <<= 1) {
            s_ += __shfl_xor(s_, off, 64);
            ss += __shfl_xor(ss, off, 64);
        }
        if (j == 0) { parts[n] = s_; parts[N_NODES + n] = ss; }
    }
}

// ---------------- multi-block reduction of parts -> stats (f64 atomics) ----------
#define RED_BLOCKS 100
__global__ __launch_bounds__(256) void k_reduce(
    const float* __restrict__ parts, double* __restrict__ stats)
{
    double s = 0.0, ss = 0.0;
    for (int i = blockIdx.x * 256 + threadIdx.x; i < N_NODES; i += RED_BLOCKS * 256) {
        s  += (double)parts[i];
        ss += (double)parts[N_NODES + i];
    }
#pragma unroll
    for (int off = 32; off > 0; off >>= 1) {
        s  += __shfl_down(s, off);
        ss += __shfl_down(ss, off);
    }
    __shared__ double sdd[8];
    int wave = threadIdx.x >> 6;
    if ((threadIdx.x & 63) == 0) { sdd[wave * 2] = s; sdd[wave * 2 + 1] = ss; }
    __syncthreads();
    if (threadIdx.x == 0) {
        double S = 0.0, SS = 0.0;
        for (int w = 0; w < 4; w++) { S += sdd[w * 2]; SS += sdd[w * 2 + 1]; }
        atomicAdd(&stats[0], S);
        atomicAdd(&stats[1], SS);
    }
}

// ---------------- graph layernorm + gamma/beta (in-place on d_out, float4) --------
__global__ __launch_bounds__(256) void k_norm(
    float* __restrict__ out, const double* __restrict__ stats,
    const float* __restrict__ gamma, const float* __restrict__ beta)
{
    int i = blockIdx.x * 256 + threadIdx.x;
    if (i >= N_NODES * DIM / 4) return;
    const double cnt = (double)N_NODES * (double)DIM;
    double mean = stats[0] / cnt;
    double var  = stats[1] / cnt - mean * mean;
    if (var < 0.0) var = 0.0;
    float mf = (float)mean;
    float inv = 1.0f / ((float)sqrt(var) + 1e-5f);
    float4 v = ((const float4*)out)[i];
    float4 gv = ((const float4*)gamma)[i & 15];
    float4 bv2 = ((const float4*)beta)[i & 15];
    v.x = (v.x - mf) * inv * gv.x + bv2.x;
    v.y = (v.y - mf) * inv * gv.y + bv2.y;
    v.z = (v.z - mf) * inv * gv.z + bv2.z;
    v.w = (v.w - mf) * inv * gv.w + bv2.w;
    ((float4*)out)[i] = v;
}

extern "C" void kernel_launch(void* const* d_in, const int* in_sizes, int n_in,
                              void* d_out, int out_size, void* d_ws, size_t ws_size,
                              hipStream_t stream) {
    const float* x     = (const float*)d_in[0];
    const int*   ei    = (const int*)d_in[1];
    const float* Wq    = (const float*)d_in[2];
    const float* bq    = (const float*)d_in[3];
    const float* Wk    = (const float*)d_in[4];
    const float* bk    = (const float*)d_in[5];
    const float* Wv    = (const float*)d_in[6];
    const float* bv    = (const float*)d_in[7];
    const float* Wsk   = (const float*)d_in[8];
    const float* bsk   = (const float*)d_in[9];
    const float* Wc    = (const float*)d_in[10];
    const float* bc    = (const float*)d_in[11];
    const float* gamma = (const float*)d_in[12];
    const float* beta  = (const float*)d_in[13];
    float* out = (float*)d_out;

    // ws layout
    float* ws = (float*)d_ws;
    const size_t NF = (size_t)N_NODES * HD;               // 6.4M floats
    float* q = ws;                                        // [N,128] f32
    unsigned char* kv = (unsigned char*)(ws + NF);        // [N,256] fp8 interleaved
    float* skipc = (float*)(kv + (size_t)N_NODES * 256);  // [N,64]  f32
    unsigned short* WallT = (unsigned short*)(skipc + (size_t)N_NODES * DIM); // [448,64]
    float* ball   = (float*)(WallT + NCOL * 64);          // [448]
    int* deg      = (int*)(ball + NCOL);                  // [N]
    unsigned short* elist = (unsigned short*)(deg + N_NODES); // [N*64] u16 ELL
    float* parts  = (float*)(elist + (size_t)N_NODES * MAXDEG); // [2,N] split
    double* stats = (double*)(parts + (size_t)N_NODES * 2);

    hipMemsetAsync(deg, 0, N_NODES * sizeof(int), stream);
    hipLaunchKernelGGL(k_pb, dim3(PREP_B + EDGE_BLKS), dim3(256), 0, stream,
                       ei, Wq, bq, Wk, bk, Wv, bv, Wsk, bsk, Wc, bc,
                       WallT, ball, deg, elist, stats);
    hipLaunchKernelGGL(k_ep, dim3(PROJ_B), dim3(256), 0, stream,
                       x, WallT, ball, q, kv, skipc);
    hipLaunchKernelGGL(k_attn, dim3(N_NODES / 4), dim3(256), 0, stream,
                       q, kv, skipc, deg, elist, out, parts);
    hipLaunchKernelGGL(k_reduce, dim3(RED_BLOCKS), dim3(256), 0, stream, parts, stats);
    hipLaunchKernelGGL(k_norm, dim3(N_NODES * DIM / 4 / 256 + 1), dim3(256), 0, stream,
                       out, stats, gamma, beta);
}

// Round 3
// 185.744 us; speedup vs baseline: 1.1322x; 1.1322x over previous
//
#include <hip/hip_runtime.h>
#include <hip/hip_bf16.h>

#define N_NODES 50000
#define N_EDGES 800000
#define DIM 64
#define NHEAD 2
#define HD 128     // NHEAD * DIM
#define NCOL 448   // 128 q + 128 k + 128 vc + 64 skipc
#define MAXDEG 64  // ELL row stride; max Poisson(16) deg over 50k nodes ~ 45

#define NBIN 196    // bins of 256 nodes: 196*256 = 50176 >= 50000
#define BCAP 6144   // bin capacity; lambda=4082, +32 sigma
#define ACH 2048    // edges per bin-block
#define BIN_BLKS 391 // ceil(800000/2048)

#define PREP_B 112  // 448*64/256
#define PROJ_B 782  // ceil(50000/64)

// q pre-scale: 1/sqrt(64) * 1/ln(2)  -> logits are in exp2 domain
#define QSCALE 0.18033688011112042f

typedef short bf16x8 __attribute__((ext_vector_type(8)));
typedef float f32x16 __attribute__((ext_vector_type(16)));
typedef float f32x2 __attribute__((ext_vector_type(2)));

__device__ __forceinline__ unsigned short f2bf(float f) {
    unsigned u = __float_as_uint(f);
    unsigned r = (u + 0x7fffu + ((u >> 16) & 1u)) >> 16;   // RNE
    return (unsigned short)r;
}
// fp8 e4m3 HW converts (gfx950 OCP): encode f32 -> 1 byte
__device__ __forceinline__ unsigned char f2fp8(float f) {
    int r = __builtin_amdgcn_cvt_pk_fp8_f32(f, f, 0, false);
    return (unsigned char)(r & 0xff);
}

// ------- merged: folded-weight prep ∥ streamlined edge binning -------
// blocks [0,PREP_B): WallT[448][64] bf16 + ball[448] (+ zero sacc)
// blocks [PREP_B..): per 2048-edge chunk: LDS-atomic rank at count time,
//   1 global atomic per bin to reserve range, direct scatter to dense runs.
//   2 barriers total (vs 36 in the old scan+reorder+flush version).
__global__ __launch_bounds__(256) void k_pb(
    const int* __restrict__ ei,
    const float* __restrict__ Wq, const float* __restrict__ bq,
    const float* __restrict__ Wk, const float* __restrict__ bk,
    const float* __restrict__ Wv, const float* __restrict__ bv,
    const float* __restrict__ Wskip, const float* __restrict__ bskip,
    const float* __restrict__ Wc, const float* __restrict__ bc,
    unsigned short* __restrict__ WallT, float* __restrict__ ball,
    int* __restrict__ bincnt, unsigned* __restrict__ bins,
    double* __restrict__ sacc)
{
    const int t = threadIdx.x;
    if (blockIdx.x < PREP_B) {
        if (blockIdx.x == 0) { sacc[t] = 0.0; sacc[256 + t] = 0.0; }
        int gid = blockIdx.x * 256 + t;   // 0..28671
        const int j = gid >> 6;   // output column 0..447
        const int d = gid & 63;   // k index
        float w, bb;
        if (j < 128) {
            w = Wq[d * HD + j] * QSCALE;
            bb = bq[j] * QSCALE;
        } else if (j < 256) {
            int jj = j - 128;
            w = Wk[d * HD + jj];
            bb = bk[jj];
        } else if (j < 384) {
            int jj = j - 256;
            int h = jj >> 6, jc = jj & 63;
            float s = 0.f, sb = 0.f;
            for (int c = 0; c < 64; c++) {
                float wc = Wc[(h * 64 + c) * DIM + jc];
                s  += Wv[d * HD + h * 64 + c] * wc;
                sb += bv[h * 64 + c] * wc;
            }
            w = s; bb = sb;
        } else {
            int jj = j - 384;
            float s = 0.f, sb = bc[jj];
            for (int c = 0; c < HD; c++) {
                float wc = Wc[c * DIM + jj];
                s  += Wskip[d * HD + c] * wc;
                sb += bskip[c] * wc;
            }
            w = s; bb = sb;
        }
        WallT[gid] = f2bf(w);
        if (d == 0) ball[j] = bb;
        return;
    }
    // ---- binning: count+rank, reserve, scatter ----
    __shared__ int hist[256];
    __shared__ int gbase[256];
    const int e0 = (blockIdx.x - PREP_B) * ACH;
    hist[t] = 0;
    __syncthreads();
    unsigned pk8[8];
    int bin8[8], sl8[8];
#pragma unroll
    for (int k = 0; k < 8; k++) {
        int e = e0 + t + k * 256;
        if (e < N_EDGES) {
            int src = ei[e];
            int d = ei[N_EDGES + e];
            int bin = d >> 8;
            pk8[k] = (unsigned)(((d & 255) << 16) | src);
            bin8[k] = bin;
            sl8[k] = atomicAdd(&hist[bin], 1);
        } else {
            bin8[k] = -1;
        }
    }
    __syncthreads();
    if (t < NBIN) {
        int h = hist[t];
        if (h > 0) gbase[t] = atomicAdd(&bincnt[t], h);
    }
    __syncthreads();
#pragma unroll
    for (int k = 0; k < 8; k++) {
        int bin = bin8[k];
        if (bin >= 0) {
            int pos = gbase[bin] + sl8[k];
            if (pos < BCAP) bins[(size_t)bin * BCAP + pos] = pk8[k];
        }
    }
}

// ------- merged: MFMA projection GEMM ∥ bin->ELL (u16, deg written directly) -------
// blocks [0,PROJ_B): one 64-node tile of [N x 64] @ [64 x 448]
//   C/D mapping: col=lane&31, row=(reg&3)+8*(reg>>2)+4*(lane>>5)
//   outputs: q f32 [N,128] | kv fp8 [N,256] interleaved | skipc f32 [N,64]
//   kv byte layout per 16B group i: [h0 ch 8i..8i+7 | h1 ch 8i..8i+7], K then V.
// blocks [PROJ_B, PROJ_B+NBIN): unpack bin, LDS per-node slots, write elist+deg
__global__ __launch_bounds__(256) void k_ep(
    const float* __restrict__ x,
    const unsigned short* __restrict__ WallT, const float* __restrict__ ball,
    float* __restrict__ q, unsigned char* __restrict__ kv, float* __restrict__ skipc,
    const int* __restrict__ bincnt, const unsigned* __restrict__ bins,
    int* __restrict__ deg, unsigned short* __restrict__ elist)
{
    const int blk = blockIdx.x;
    const int t = threadIdx.x;
    if (blk >= PROJ_B) {
        const int bin = blk - PROJ_B;
        __shared__ int nodecnt[256];
        nodecnt[t] = 0;
        __syncthreads();
        int cnt = bincnt[bin]; if (cnt > BCAP) cnt = BCAP;
        const unsigned* bp = bins + (size_t)bin * BCAP;
        for (int i = t; i < cnt; i += 256) {
            unsigned p = bp[i];
            int local = p >> 16;
            int src = p & 0xffff;
            int sl = atomicAdd(&nodecnt[local], 1);
            if (sl < MAXDEG)
                elist[((size_t)((bin << 8) | local)) * MAXDEG + sl] = (unsigned short)src;
        }
        __syncthreads();
        int node = (bin << 8) + t;
        if (node < N_NODES) {
            int dgv = nodecnt[t];
            deg[node] = dgv > MAXDEG ? MAXDEG : dgv;
        }
        return;
    }
    const int w = t >> 6;
    const int lane = t & 63;
    const int col = lane & 31;
    const int khalf = lane >> 5;
    const int n0 = blk * 64 + (w >> 1) * 32;
    const int ct0 = (w & 1) * 7;
    const int rowbase = 4 * khalf;

    int nread = n0 + col; if (nread >= N_NODES) nread = N_NODES - 1;
    const float* ap = x + (size_t)nread * 64 + khalf * 8;
    bf16x8 afrag[4];
#pragma unroll
    for (int kk = 0; kk < 4; kk++) {
        float4 xa = *((const float4*)(ap + kk * 16));
        float4 xb4 = *((const float4*)(ap + kk * 16 + 4));
        bf16x8 f;
        f[0] = (short)f2bf(xa.x); f[1] = (short)f2bf(xa.y);
        f[2] = (short)f2bf(xa.z); f[3] = (short)f2bf(xa.w);
        f[4] = (short)f2bf(xb4.x); f[5] = (short)f2bf(xb4.y);
        f[6] = (short)f2bf(xb4.z); f[7] = (short)f2bf(xb4.w);
        afrag[kk] = f;
    }

    for (int tt = 0; tt < 7; tt++) {
        const int gc = (ct0 + tt) * 32 + col;
        const float b = ball[gc];
        f32x16 acc;
#pragma unroll
        for (int r = 0; r < 16; r++) acc[r] = b;
        const unsigned short* bp = WallT + (size_t)gc * 64 + khalf * 8;
#pragma unroll
        for (int kk = 0; kk < 4; kk++) {
            bf16x8 bfrag = *((const bf16x8*)(bp + kk * 16));
            acc = __builtin_amdgcn_mfma_f32_32x32x16_bf16(afrag[kk], bfrag, acc, 0, 0, 0);
        }
        if (gc < 128) {
#pragma unroll
            for (int r = 0; r < 16; r++) {
                int node = n0 + (r & 3) + 8 * (r >> 2) + rowbase;
                if (node < N_NODES) q[(size_t)node * HD + gc] = acc[r];
            }
        } else if (gc < 384) {
            int ch = gc - 128;           // 0..255 (K: 0..127, V: 128..255)
            int half = ch >> 7;          // 0=K, 1=V
            int cc = ch & 127;
            int h = cc >> 6, c = cc & 63;
            int pos = half * 128 + ((c >> 3) << 4) + (h << 3) + (c & 7);
#pragma unroll
            for (int r = 0; r < 16; r++) {
                int node = n0 + (r & 3) + 8 * (r >> 2) + rowbase;
                if (node < N_NODES) kv[(size_t)node * 256 + pos] = f2fp8(acc[r]);
            }
        } else {
#pragma unroll
            for (int r = 0; r < 16; r++) {
                int node = n0 + (r & 3) + 8 * (r >> 2) + rowbase;
                if (node < N_NODES) skipc[(size_t)node * DIM + (gc - 384)] = acc[r];
            }
        }
    }
}

// -------- fused attention: fp8 kv gather, 8-edge-parallel softmax + skipc + stats ----
// 4 waves/block, one wave per dst node; 8 groups x 8 lanes, one edge per group/iter.
// kv row (256B fp8): 16B groups [h0 8ch | h1 8ch], K region then V region.
// One uint4 load each for K and V per lane. q pre-scaled -> exp2 direct.
// Per-wave (s,ss) accumulated by f64 atomics into 256 hashed slots (no k_reduce).
__global__ __launch_bounds__(256) void k_attn(
    const float* __restrict__ q, const unsigned char* __restrict__ kv,
    const float* __restrict__ skipc,
    const int* __restrict__ deg, const unsigned short* __restrict__ elist,
    float* __restrict__ out, double* __restrict__ sacc)
{
    const int w = threadIdx.x >> 6;
    const int lane = threadIdx.x & 63;
    const int g = lane >> 3;   // edge group 0..7
    const int j = lane & 7;    // channels 8j..8j+7 of each head
    const int n = blockIdx.x * 4 + w;
    const f32x2* qp = (const f32x2*)(q + (size_t)n * HD);
    f32x2 q0[4], q1[4];
#pragma unroll
    for (int i = 0; i < 4; i++) { q0[i] = qp[4 * j + i]; q1[i] = qp[32 + 4 * j + i]; }
    const int myE = elist[(size_t)n * MAXDEG + lane];   // full ELL row, coalesced u16
    f32x2 acc0[4], acc1[4];
#pragma unroll
    for (int i = 0; i < 4; i++) {
        acc0[i] = (f32x2){0.f, 0.f};
        acc1[i] = (f32x2){0.f, 0.f};
    }
    float l0 = 0.f, l1 = 0.f;
    int dg = deg[n]; if (dg > MAXDEG) dg = MAXDEG;
    for (int b0 = 0; b0 < dg; b0 += 8) {
        int idx = b0 + g;
        bool valid = idx < dg;
        int s = __shfl(myE, valid ? idx : 0, 64);
        const uint4* kp = (const uint4*)(kv + (size_t)s * 256);
        uint4 K = kp[j];       // h0 c8j..8j+7 (x,y) | h1 c8j..8j+7 (z,w)
        uint4 V = kp[8 + j];
        f32x2 p0v = q0[0] * __builtin_amdgcn_cvt_pk_f32_fp8(K.x, false);
        p0v += q0[1] * __builtin_amdgcn_cvt_pk_f32_fp8(K.x, true);
        p0v += q0[2] * __builtin_amdgcn_cvt_pk_f32_fp8(K.y, false);
        p0v += q0[3] * __builtin_amdgcn_cvt_pk_f32_fp8(K.y, true);
        f32x2 p1v = q1[0] * __builtin_amdgcn_cvt_pk_f32_fp8(K.z, false);
        p1v += q1[1] * __builtin_amdgcn_cvt_pk_f32_fp8(K.z, true);
        p1v += q1[2] * __builtin_amdgcn_cvt_pk_f32_fp8(K.w, false);
        p1v += q1[3] * __builtin_amdgcn_cvt_pk_f32_fp8(K.w, true);
        float p0 = p0v[0] + p0v[1];
        float p1 = p1v[0] + p1v[1];
#pragma unroll
        for (int off = 1; off < 8; off <<= 1) {
            p0 += __shfl_xor(p0, off, 64);
            p1 += __shfl_xor(p1, off, 64);
        }
        float w0 = valid ? __builtin_amdgcn_exp2f(p0) : 0.f;
        float w1 = valid ? __builtin_amdgcn_exp2f(p1) : 0.f;
        l0 += w0; l1 += w1;
        f32x2 w0v = {w0, w0}, w1v = {w1, w1};
        acc0[0] += w0v * __builtin_amdgcn_cvt_pk_f32_fp8(V.x, false);
        acc0[1] += w0v * __builtin_amdgcn_cvt_pk_f32_fp8(V.x, true);
        acc0[2] += w0v * __builtin_amdgcn_cvt_pk_f32_fp8(V.y, false);
        acc0[3] += w0v * __builtin_amdgcn_cvt_pk_f32_fp8(V.y, true);
        acc1[0] += w1v * __builtin_amdgcn_cvt_pk_f32_fp8(V.z, false);
        acc1[1] += w1v * __builtin_amdgcn_cvt_pk_f32_fp8(V.z, true);
        acc1[2] += w1v * __builtin_amdgcn_cvt_pk_f32_fp8(V.w, false);
        acc1[3] += w1v * __builtin_amdgcn_cvt_pk_f32_fp8(V.w, true);
    }
    // ---- cross-group reduction (once per node) ----
    float* a0 = (float*)acc0;
    float* a1 = (float*)acc1;
#pragma unroll
    for (int off = 8; off < 64; off <<= 1) {
        l0 += __shfl_xor(l0, off, 64);
        l1 += __shfl_xor(l1, off, 64);
#pragma unroll
        for (int i = 0; i < 8; i++) {
            a0[i] += __shfl_xor(a0[i], off, 64);
            a1[i] += __shfl_xor(a1[i], off, 64);
        }
    }
    if (g == 0) {
        float inv0 = 1.f / (l0 + 1e-16f), inv1 = 1.f / (l1 + 1e-16f);
        const float4* sk = (const float4*)(skipc + (size_t)n * DIM);
        float4 sa = sk[2 * j], sb = sk[2 * j + 1];
        float o[8];
        o[0] = a0[0] * inv0 + a1[0] * inv1 + sa.x;
        o[1] = a0[1] * inv0 + a1[1] * inv1 + sa.y;
        o[2] = a0[2] * inv0 + a1[2] * inv1 + sa.z;
        o[3] = a0[3] * inv0 + a1[3] * inv1 + sa.w;
        o[4] = a0[4] * inv0 + a1[4] * inv1 + sb.x;
        o[5] = a0[5] * inv0 + a1[5] * inv1 + sb.y;
        o[6] = a0[6] * inv0 + a1[6] * inv1 + sb.z;
        o[7] = a0[7] * inv0 + a1[7] * inv1 + sb.w;
        float4 r0 = {o[0], o[1], o[2], o[3]}, r1 = {o[4], o[5], o[6], o[7]};
        float4* op = (float4*)(out + (size_t)n * DIM);
        op[2 * j] = r0; op[2 * j + 1] = r1;
        float s_ = 0.f, ss = 0.f;
#pragma unroll
        for (int i = 0; i < 8; i++) { s_ += o[i]; ss += o[i] * o[i]; }
#pragma unroll
        for (int off = 1; off < 8; off <<= 1) {
            s_ += __shfl_xor(s_, off, 64);
            ss += __shfl_xor(ss, off, 64);
        }
        if (j == 0) {
            int slot = n & 255;
            atomicAdd(&sacc[slot], (double)s_);
            atomicAdd(&sacc[256 + slot], (double)ss);
        }
    }
}

// ---------------- graph layernorm + gamma/beta (reduces sacc per block) --------
__global__ __launch_bounds__(256) void k_norm(
    float* __restrict__ out, const double* __restrict__ sacc,
    const float* __restrict__ gamma, const float* __restrict__ beta)
{
    const int t = threadIdx.x;
    __shared__ double red[8];
    double s = sacc[t];
    double ss = sacc[256 + t];
#pragma unroll
    for (int off = 32; off > 0; off >>= 1) {
        s  += __shfl_down(s, off);
        ss += __shfl_down(ss, off);
    }
    int wv = t >> 6;
    if ((t & 63) == 0) { red[wv * 2] = s; red[wv * 2 + 1] = ss; }
    __syncthreads();
    double S  = red[0] + red[2] + red[4] + red[6];
    double SS = red[1] + red[3] + red[5] + red[7];
    const double cnt = (double)N_NODES * (double)DIM;
    double mean = S / cnt;
    double var  = SS / cnt - mean * mean;
    if (var < 0.0) var = 0.0;
    float mf = (float)mean;
    float inv = 1.0f / ((float)sqrt(var) + 1e-5f);
    int i = blockIdx.x * 256 + t;
    if (i >= N_NODES * DIM / 4) return;
    float4 v = ((const float4*)out)[i];
    float4 gv = ((const float4*)gamma)[i & 15];
    float4 bv2 = ((const float4*)beta)[i & 15];
    v.x = (v.x - mf) * inv * gv.x + bv2.x;
    v.y = (v.y - mf) * inv * gv.y + bv2.y;
    v.z = (v.z - mf) * inv * gv.z + bv2.z;
    v.w = (v.w - mf) * inv * gv.w + bv2.w;
    ((float4*)out)[i] = v;
}

extern "C" void kernel_launch(void* const* d_in, const int* in_sizes, int n_in,
                              void* d_out, int out_size, void* d_ws, size_t ws_size,
                              hipStream_t stream) {
    const float* x     = (const float*)d_in[0];
    const int*   ei    = (const int*)d_in[1];
    const float* Wq    = (const float*)d_in[2];
    const float* bq    = (const float*)d_in[3];
    const float* Wk    = (const float*)d_in[4];
    const float* bk    = (const float*)d_in[5];
    const float* Wv    = (const float*)d_in[6];
    const float* bv    = (const float*)d_in[7];
    const float* Wsk   = (const float*)d_in[8];
    const float* bsk   = (const float*)d_in[9];
    const float* Wc    = (const float*)d_in[10];
    const float* bc    = (const float*)d_in[11];
    const float* gamma = (const float*)d_in[12];
    const float* beta  = (const float*)d_in[13];
    float* out = (float*)d_out;

    // ws layout (sacc first for 8B alignment)
    double* sacc = (double*)d_ws;                          // [512] f64 stat slots
    float* ws = (float*)(sacc + 512);
    const size_t NF = (size_t)N_NODES * HD;                // 6.4M floats
    float* q = ws;                                         // [N,128] f32
    unsigned char* kv = (unsigned char*)(ws + NF);         // [N,256] fp8 interleaved
    float* skipc = (float*)(kv + (size_t)N_NODES * 256);   // [N,64]  f32
    unsigned short* WallT = (unsigned short*)(skipc + (size_t)N_NODES * DIM); // [448,64]
    float* ball   = (float*)(WallT + NCOL * 64);           // [448]
    int* bincnt   = (int*)(ball + NCOL);                   // [256]
    unsigned* bins = (unsigned*)(bincnt + 256);            // [NBIN*BCAP]
    int* deg      = (int*)(bins + (size_t)NBIN * BCAP);    // [N]
    unsigned short* elist = (unsigned short*)(deg + N_NODES); // [N*64] u16 ELL

    hipMemsetAsync(bincnt, 0, 256 * sizeof(int), stream);
    hipLaunchKernelGGL(k_pb, dim3(PREP_B + BIN_BLKS), dim3(256), 0, stream,
                       ei, Wq, bq, Wk, bk, Wv, bv, Wsk, bsk, Wc, bc,
                       WallT, ball, bincnt, bins, sacc);
    hipLaunchKernelGGL(k_ep, dim3(PROJ_B + NBIN), dim3(256), 0, stream,
                       x, WallT, ball, q, kv, skipc, bincnt, bins, deg, elist);
    hipLaunchKernelGGL(k_attn, dim3(N_NODES / 4), dim3(256), 0, stream,
                       q, kv, skipc, deg, elist, out, sacc);
    hipLaunchKernelGGL(k_norm, dim3(N_NODES * DIM / 4 / 256 + 1), dim3(256), 0, stream,
                       out, sacc, gamma, beta);
}